// Round 1
// 1167.178 us; speedup vs baseline: 1.0447x; 1.0447x over previous
//
#include <hip/hip_runtime.h>
#include <cstdint>

// ---------------- problem dims (fixed by the reference) ----------------
static constexpr int Mdim = 8192;     // B*S = 4*2048
static constexpr int Ndim = 11008;    // O
static constexpr int Kdim = 4096;     // I
static constexpr int NGRP = 32;       // I / 128

#define BM 256
#define BN 256
#define BK 64
#define NT (Kdim / BK)                      // 64 K-tiles
#define NBLK ((Mdim / BM) * (Ndim / BN))    // 32 * 43 = 1376 (divisible by 8)
#define CPX (NBLK / 8)                      // 172 blocks per XCD

typedef __bf16 bf16x8 __attribute__((ext_vector_type(8)));
typedef float floatx4 __attribute__((ext_vector_type(4)));
typedef unsigned short ushort8_t __attribute__((ext_vector_type(8)));

// RTNE fp32 -> bf16 (inputs are finite; no NaN path needed)
__device__ __forceinline__ unsigned short f2bf(float f) {
  union { float f; uint32_t u; } v; v.f = f;
  uint32_t u = v.u;
  return (unsigned short)((u + 0x7fffu + ((u >> 16) & 1u)) >> 16);
}

// async global->LDS, 16B per lane; LDS dest = wave-uniform base + lane*16
__device__ __forceinline__ void gload16(const void* g, void* l) {
  __builtin_amdgcn_global_load_lds(
      (const __attribute__((address_space(1))) void*)g,
      (__attribute__((address_space(3))) void*)l, 16, 0, 0);
}

// ---------------- prepass 1: x fp32 -> bf16 ----------------
__global__ __launch_bounds__(256) void cast_x_kernel(const float* __restrict__ x,
                                                     unsigned short* __restrict__ xb) {
  int i = blockIdx.x * 256 + threadIdx.x;   // 4 floats / thread
  float4 f = ((const float4*)x)[i];
  ushort4 o;
  o.x = f2bf(f.x); o.y = f2bf(f.y); o.z = f2bf(f.z); o.w = f2bf(f.w);
  ((ushort4*)xb)[i] = o;
}

// ---------------- prepass 2: dequant int4 -> bf16, W[N][K] ----------------
__global__ __launch_bounds__(256) void dequant_w_kernel(const int* __restrict__ qw,
                                                        const float* __restrict__ scale,
                                                        const float* __restrict__ zp,
                                                        unsigned short* __restrict__ wb) {
  int idx = blockIdx.x * 256 + threadIdx.x;   // [0, O*512): 4 int32 / thread
  int o  = idx >> 9;
  int j4 = idx & 511;          // chunk of 4 int32 => 8 weights
  int g  = j4 >> 4;            // 4-int chunks never straddle a group
  float s = scale[o * NGRP + g];
  float z = zp[o * NGRP + g];
  int4 q = ((const int4*)qw)[idx];
  int qs[4] = {q.x, q.y, q.z, q.w};
  ushort8_t r;
#pragma unroll
  for (int t = 0; t < 4; ++t) {
    float lo = (float)(qs[t] & 15);
    float hi = (float)((qs[t] >> 4) & 15);
    r[2 * t]     = f2bf((lo - z) * s);
    r[2 * t + 1] = f2bf((hi - z) * s);
  }
  *(ushort8_t*)(wb + (size_t)o * Kdim + (size_t)j4 * 8) = r;
}

// ---------------- GEMM: C[M][N] = Xb[M][K] * Wb[N][K]^T + bias ----------------
// 256x256 tile, BK=64, 8 waves (2M x 4N, each 128x64), 2 LDS buffers (128 KiB).
// Counted-vmcnt pipeline: tile t+2 is staged into the buffer consumed by tile t,
// and the K-tile boundary waits vmcnt(8) (tile t+1's 8 loads) while tile t+2's
// 8 loads stay in flight ACROSS the barrier. No __syncthreads / no vmcnt(0)
// drain in the main loop.
// LDS rows are XOR-swizzled at 16B-chunk granularity: chunk c of row r lives at
// chunk c ^ (r & 7); staging realizes this by pre-swizzling the per-lane global
// source while keeping the global_load_lds destination linear.
__global__ __launch_bounds__(512, 2) void gemm_kernel(const unsigned short* __restrict__ Xb,
                                                      const unsigned short* __restrict__ Wb,
                                                      const float* __restrict__ bias,
                                                      float* __restrict__ out) {
  // [2 buffers][512 rows (A:0-255 = X rows, B:256-511 = W rows)][64 bf16]
  __shared__ unsigned short lds[2 * 512 * BK];

  const int tid  = threadIdx.x;
  const int wave = tid >> 6;
  const int lane = tid & 63;
  const int wm   = wave >> 2;   // 0..1 : 128-row band
  const int wn   = wave & 3;    // 0..3 : 64-col band

  // XCD-aware swizzle: 32 consecutive wg (= the 32 CUs of one XCD) share one
  // B panel (2 MB -> L2-resident) and sweep all 32 A panels (LLC-resident).
  const int bid  = blockIdx.x;
  const int wg   = (bid & 7) * CPX + (bid >> 3);
  const int mb   = wg & 31;     // M fast within an XCD
  const int nb   = wg >> 5;     // 0..42
  const int row0 = mb * BM;
  const int col0 = nb * BN;

  // staging sources: 8 x 16B chunks per thread per K-tile, 8 lanes cover one
  // 128B row (chunk-permuted by the swizzle) -> fully coalesced.
  const unsigned short* gp[8];
#pragma unroll
  for (int j = 0; j < 8; ++j) {
    const int q   = j * 512 + tid;          // linear LDS chunk 0..4095
    const int row = q >> 3;                 // 0..511
    const int cg  = (q & 7) ^ (row & 7);    // swizzled global source chunk
    gp[j] = (row < 256)
          ? Xb + (size_t)(row0 + row) * Kdim + cg * 8
          : Wb + (size_t)(col0 + row - 256) * Kdim + cg * 8;
  }
  const int ldsoff = wave * 64 * 8;         // ushort units

#define STAGE(Lb) do { _Pragma("unroll")                                  \
  for (int j = 0; j < 8; ++j) {                                           \
    gload16(gp[j], (Lb) + ldsoff + j * 512 * 8);                          \
    gp[j] += BK;                                                          \
  } } while (0)

  floatx4 acc[8][4];
#pragma unroll
  for (int i = 0; i < 8; ++i)
#pragma unroll
    for (int j = 0; j < 4; ++j) acc[i][j] = (floatx4){0.f, 0.f, 0.f, 0.f};

  // one compute phase: 12 ds_read_b128 + 32 MFMA for one K-half (kk = 0 or 32)
  auto phase = [&](const unsigned short* L, int kk) {
    bf16x8 af[8], bf[4];
    const int co = ((((kk >> 3) + (lane >> 4)) ^ (lane & 7)) << 3);
    const int rA = wm * 128 + (lane & 15);
    const int rB = 256 + wn * 64 + (lane & 15);
#pragma unroll
    for (int m = 0; m < 8; ++m) af[m] = *(const bf16x8*)&L[(rA + m * 16) * BK + co];
#pragma unroll
    for (int n = 0; n < 4; ++n) bf[n] = *(const bf16x8*)&L[(rB + n * 16) * BK + co];
    __builtin_amdgcn_s_setprio(1);
#pragma unroll
    for (int m = 0; m < 8; ++m)
#pragma unroll
      for (int n = 0; n < 4; ++n)
        acc[m][n] = __builtin_amdgcn_mfma_f32_16x16x32_bf16(af[m], bf[n], acc[m][n], 0, 0, 0);
    __builtin_amdgcn_s_setprio(0);
  };

  // prologue: tile 0 -> buf0, tile 1 -> buf1; wait only for tile 0 (8 loads)
  STAGE(lds);
  STAGE(lds + 512 * BK);
  asm volatile("s_waitcnt vmcnt(8)" ::: "memory");
  __builtin_amdgcn_s_barrier();
  __builtin_amdgcn_sched_barrier(0);

  for (int t = 0; t < NT; ++t) {
    unsigned short* L = (unsigned short*)lds + (t & 1) * (512 * BK);

    phase(L, 0);
    __builtin_amdgcn_s_barrier();     // mid-tile phase lock (waves stay in step)
    phase(L, 32);

    if (t < NT - 2) {
      asm volatile("" ::: "memory");
      __builtin_amdgcn_s_barrier();   // every wave done reading this buffer
      STAGE(L);                       // tile t+2 overwrites it (8 loads issued)
      // counted: wait for tile t+1's 8 loads; leave tile t+2's 8 in flight
      asm volatile("s_waitcnt vmcnt(8)" ::: "memory");
      __builtin_amdgcn_s_barrier();   // buffer (t+1)&1 now ready for all waves
      __builtin_amdgcn_sched_barrier(0);
    } else if (t == NT - 2) {
      // single drain at the end of the pipeline (last tile's loads)
      asm volatile("s_waitcnt vmcnt(0)" ::: "memory");
      __builtin_amdgcn_s_barrier();
      __builtin_amdgcn_sched_barrier(0);
    }
  }
#undef STAGE

  // epilogue: C/D layout col=lane&15, row=(lane>>4)*4+reg; non-temporal stores
  // keep the 360 MB output stream from evicting X/W out of L2/LLC.
#pragma unroll
  for (int n = 0; n < 4; ++n) {
    const int nn = col0 + wn * 64 + n * 16 + (lane & 15);
    const float bv = bias[nn];
#pragma unroll
    for (int m = 0; m < 8; ++m) {
      const int m0 = row0 + wm * 128 + m * 16 + (lane >> 4) * 4;
#pragma unroll
      for (int r = 0; r < 4; ++r)
        __builtin_nontemporal_store(acc[m][n][r] + bv, &out[(size_t)(m0 + r) * Ndim + nn]);
    }
  }
}

extern "C" void kernel_launch(void* const* d_in, const int* in_sizes, int n_in,
                              void* d_out, int out_size, void* d_ws, size_t ws_size,
                              hipStream_t stream) {
  const float* x     = (const float*)d_in[0];
  const int*   qw    = (const int*)d_in[1];
  const float* scale = (const float*)d_in[2];
  const float* zp    = (const float*)d_in[3];
  const float* bias  = (const float*)d_in[4];
  float* out = (float*)d_out;

  // workspace: Xb[M*K] bf16 (64 MiB), then Wb[N*K] bf16 (86 MiB)
  unsigned short* xb = (unsigned short*)d_ws;
  unsigned short* wb = xb + (size_t)Mdim * Kdim;

  cast_x_kernel<<<(Mdim * Kdim / 4) / 256, 256, 0, stream>>>(x, xb);
  dequant_w_kernel<<<(Ndim * 512) / 256, 256, 0, stream>>>(qw, scale, zp, wb);
  gemm_kernel<<<NBLK, 512, 0, stream>>>(xb, wb, bias, out);
}